// Round 1
// baseline (8702.419 us; speedup 1.0000x reference)
//
#include <hip/hip_runtime.h>
#include <hip/hip_bf16.h>

// LSTM Seq2Seq persistent kernel, fp16 MFMA + fp32 cell state.
// Strategy: one cooperative kernel, 256 blocks x 256 threads (1 block/CU),
// 264 grid barriers (2/enc step, 3/dec step). Each block owns a
// 64(batch) x 16(hidden) tile and computes all four gate slices so the
// LSTM pointwise epilogue fuses into the GEMM (z never hits memory).

typedef _Float16 half8 __attribute__((ext_vector_type(8)));
typedef float floatx4 __attribute__((ext_vector_type(4)));

#define NBLK 256
#define NTHR 256

__device__ __forceinline__ float sigf(float x) { return 1.f / (1.f + __expf(-x)); }
__device__ __forceinline__ float tanhf_(float x) { return 1.f - 2.f / (__expf(2.f * x) + 1.f); }

// ---------------- grid barrier (device-scope, monotonic counter) ----------------
__device__ __forceinline__ void gbar(unsigned* bar, unsigned* tgt) {
  __syncthreads();  // drains vmem (s_waitcnt vmcnt(0)) before barrier
  if (threadIdx.x == 0) {
    *tgt += gridDim.x;
    __hip_atomic_fetch_add(bar, 1u, __ATOMIC_ACQ_REL, __HIP_MEMORY_SCOPE_AGENT);
    while (__hip_atomic_load(bar, __ATOMIC_ACQUIRE, __HIP_MEMORY_SCOPE_AGENT) < *tgt)
      __builtin_amdgcn_s_sleep(2);
    __threadfence();  // belt-and-suspenders acquire for the whole CU
  }
  __syncthreads();
}

// ---------------- prep kernel: fp16 weight repack + transposes + init ----------------
__global__ void prep_kernel(
    const float* __restrict__ src,
    const float* __restrict__ eWih0, const float* __restrict__ eWhh0,
    const float* __restrict__ ebih0, const float* __restrict__ ebhh0,
    const float* __restrict__ eWih1, const float* __restrict__ eWhh1,
    const float* __restrict__ ebih1, const float* __restrict__ ebhh1,
    const float* __restrict__ dWih0, const float* __restrict__ dWhh0,
    const float* __restrict__ dbih0, const float* __restrict__ dbhh0,
    const float* __restrict__ dWih1, const float* __restrict__ dWhh1,
    const float* __restrict__ dbih1, const float* __restrict__ dbhh1,
    _Float16* W0e, _Float16* W1e, _Float16* W0d, _Float16* W1d,
    float* bs, _Float16* H0, _Float16* A1, float* c0, float* c1,
    _Float16* Xe, _Float16* Xd, unsigned* bar)
{
  const int T = gridDim.x * blockDim.x;
  const int idx = blockIdx.x * blockDim.x + threadIdx.x;

  // L0 weights: row r = [Whh0[r][0..511] | Wih0[r][0..31]], stride 544
  for (int i = idx; i < 2048 * 544; i += T) {
    int r = i / 544, k = i - r * 544;
    W0e[i] = (_Float16)(k < 512 ? eWhh0[r * 512 + k] : eWih0[r * 32 + k - 512]);
    W0d[i] = (_Float16)(k < 512 ? dWhh0[r * 512 + k] : dWih0[r * 32 + k - 512]);
  }
  // L1 weights: row r = [Whh1[r][0..511] | Wih1[r][0..511]], stride 1024
  for (int i = idx; i < 2048 * 1024; i += T) {
    int r = i >> 10, k = i & 1023;
    W1e[i] = (_Float16)(k < 512 ? eWhh1[r * 512 + k] : eWih1[r * 512 + k - 512]);
    W1d[i] = (_Float16)(k < 512 ? dWhh1[r * 512 + k] : dWih1[r * 512 + k - 512]);
  }
  // combined biases bih+bhh: [b0e | b1e | b0d | b1d], each 2048
  for (int i = idx; i < 2048; i += T) {
    bs[i]        = ebih0[i] + ebhh0[i];
    bs[2048 + i] = ebih1[i] + ebhh1[i];
    bs[4096 + i] = dbih0[i] + dbhh0[i];
    bs[6144 + i] = dbih1[i] + dbhh1[i];
  }
  // encoder inputs step-major: Xe[t][b][f] = src[b][t][f]
  for (int i = idx; i < 96 * 512 * 32; i += T) {
    int t = i / (512 * 32); int rem = i - t * 512 * 32; int b = rem >> 5; int f = rem & 31;
    Xe[i] = (_Float16)src[(size_t)b * 96 * 32 + t * 32 + f];
  }
  // decoder x_init = src[:, 95, :]
  for (int i = idx; i < 512 * 32; i += T) {
    int b = i >> 5, f = i & 31;
    Xd[i] = (_Float16)src[(size_t)b * 96 * 32 + 95 * 32 + f];
  }
  // zero states
  for (int i = idx; i < 2 * 512 * 512; i += T) H0[i] = (_Float16)0.f;
  for (int i = idx; i < 2 * 512 * 1024; i += T) A1[i] = (_Float16)0.f;
  for (int i = idx; i < 512 * 512; i += T) { c0[i] = 0.f; c1[i] = 0.f; }
  if (idx == 0) *bar = 0u;
}

// ---------------- fused GEMM + LSTM-gate phase ----------------
// Block tile: 64 batch rows x 16 hidden cols (= 64 z cols across 4 gates).
// Wave w handles the 16-row batch subtile m0 = (blk&7)*64 + w*16.
// MFMA 16x16x32 f16: A[m=lane&15][k=(lane>>4)*8+j], B[n=lane&15][k=...],
// D: col=lane&15, row=(lane>>4)*4+reg.
template <int AS, int XK, int WS, int KH, int D1, int D2>
__device__ __forceinline__ void layer_phase(
    const _Float16* __restrict__ A, const _Float16* __restrict__ X,
    const _Float16* __restrict__ W, const float* __restrict__ bsum,
    float* __restrict__ c, _Float16* dst1, _Float16* dst2,
    int m0, int row_a, int kq)
{
  const int n = ((int)blockIdx.x >> 3) * 16 + row_a;  // hidden col (also D col)
  floatx4 acc[4];
#pragma unroll
  for (int g = 0; g < 4; ++g) {
    float b = bsum[g * 512 + n];
    acc[g] = (floatx4){b, b, b, b};
  }
  const _Float16* arow = A + (size_t)(m0 + row_a) * AS + kq * 8;
  const _Float16* wr0 = W + (size_t)(0 * 512 + n) * WS + kq * 8;
  const _Float16* wr1 = W + (size_t)(1 * 512 + n) * WS + kq * 8;
  const _Float16* wr2 = W + (size_t)(2 * 512 + n) * WS + kq * 8;
  const _Float16* wr3 = W + (size_t)(3 * 512 + n) * WS + kq * 8;
#pragma unroll 8
  for (int k0 = 0; k0 < KH; k0 += 32) {
    half8 af = *(const half8*)(arow + k0);
    half8 b0 = *(const half8*)(wr0 + k0);
    half8 b1 = *(const half8*)(wr1 + k0);
    half8 b2 = *(const half8*)(wr2 + k0);
    half8 b3 = *(const half8*)(wr3 + k0);
    acc[0] = __builtin_amdgcn_mfma_f32_16x16x32_f16(af, b0, acc[0], 0, 0, 0);
    acc[1] = __builtin_amdgcn_mfma_f32_16x16x32_f16(af, b1, acc[1], 0, 0, 0);
    acc[2] = __builtin_amdgcn_mfma_f32_16x16x32_f16(af, b2, acc[2], 0, 0, 0);
    acc[3] = __builtin_amdgcn_mfma_f32_16x16x32_f16(af, b3, acc[3], 0, 0, 0);
  }
  if constexpr (XK > 0) {  // x-part: K=32 chunk, weights at row offset KH
    half8 af = *(const half8*)(X + (size_t)(m0 + row_a) * XK + kq * 8);
    half8 b0 = *(const half8*)(wr0 + KH);
    half8 b1 = *(const half8*)(wr1 + KH);
    half8 b2 = *(const half8*)(wr2 + KH);
    half8 b3 = *(const half8*)(wr3 + KH);
    acc[0] = __builtin_amdgcn_mfma_f32_16x16x32_f16(af, b0, acc[0], 0, 0, 0);
    acc[1] = __builtin_amdgcn_mfma_f32_16x16x32_f16(af, b1, acc[1], 0, 0, 0);
    acc[2] = __builtin_amdgcn_mfma_f32_16x16x32_f16(af, b2, acc[2], 0, 0, 0);
    acc[3] = __builtin_amdgcn_mfma_f32_16x16x32_f16(af, b3, acc[3], 0, 0, 0);
  }
  // fused LSTM gate epilogue (i,f,g,o = acc[0..3])
#pragma unroll
  for (int j = 0; j < 4; ++j) {
    int br = m0 + kq * 4 + j;  // batch row (D row mapping)
    float iv = acc[0][j], fv = acc[1][j], gv = acc[2][j], ov = acc[3][j];
    float* cp = c + (size_t)br * 512 + n;
    float cn = sigf(fv) * (*cp) + sigf(iv) * tanhf_(gv);
    float hn = sigf(ov) * tanhf_(cn);
    *cp = cn;
    _Float16 hh = (_Float16)hn;
    dst1[(size_t)br * D1 + n] = hh;
    if constexpr (D2 > 0) dst2[(size_t)br * D2 + n] = hh;
  }
}

// ---------------- decoder FC heads: out1 (scalar) + out4 (next x) ----------------
__device__ __forceinline__ void fc_phase(const _Float16* __restrict__ h1,
    const float* __restrict__ fc1w, const float* __restrict__ fc1b,
    const float* __restrict__ fc4w, const float* __restrict__ fc4b,
    float* __restrict__ out, _Float16* __restrict__ Xd, int t)
{
  if (blockIdx.x < 128) {
    int rl = threadIdx.x >> 6;     // 4 batch rows per block
    int j = threadIdx.x & 63;      // output index: 0..31 -> fc4, 32 -> fc1
    if (j < 33) {
      int b = (int)blockIdx.x * 4 + rl;
      const _Float16* hr = h1 + (size_t)b * 1024;  // h1 half of A1 row
      const float* w = (j == 32) ? fc1w : (fc4w + j * 512);
      float acc = 0.f;
#pragma unroll 8
      for (int k = 0; k < 512; ++k) acc += (float)hr[k] * w[k];
      if (j == 32) out[b * 24 + t] = acc + fc1b[0];
      else Xd[b * 32 + j] = (_Float16)(acc + fc4b[j]);
    }
  }
}

// ---------------- persistent recurrence kernel ----------------
__global__ void __launch_bounds__(NTHR, 1) lstm_main(
    const _Float16* __restrict__ W0e, const _Float16* __restrict__ W1e,
    const _Float16* __restrict__ W0d, const _Float16* __restrict__ W1d,
    const float* __restrict__ bs,
    _Float16* H0, _Float16* A1, float* c0, float* c1,
    const _Float16* __restrict__ Xe, _Float16* Xd,
    const float* __restrict__ fc1w, const float* __restrict__ fc1b,
    const float* __restrict__ fc4w, const float* __restrict__ fc4b,
    float* out, unsigned* bar)
{
  const int tid = threadIdx.x;
  const int lane = tid & 63, wv = tid >> 6;
  const int m0 = ((int)blockIdx.x & 7) * 64 + wv * 16;
  const int row_a = lane & 15, kq = lane >> 4;
  unsigned tgt = 0;

  for (int s = 0; s < 120; ++s) {
    const bool enc = (s < 96);
    const _Float16* W0 = enc ? W0e : W0d;
    const _Float16* W1 = enc ? W1e : W1d;
    const float* bs0 = bs + (enc ? 0 : 4096);
    const float* bs1 = bs + (enc ? 2048 : 6144);
    const _Float16* xp = enc ? (Xe + (size_t)s * 512 * 32) : Xd;
    _Float16* H0p = H0 + (size_t)(s & 1) * 512 * 512;        // read: h0(s-1)
    _Float16* H0q = H0 + (size_t)((s + 1) & 1) * 512 * 512;  // write: h0(s)
    _Float16* A1p = A1 + (size_t)(s & 1) * 512 * 1024;       // [h1(s-1) | h0(s)]
    _Float16* A1q = A1 + (size_t)((s + 1) & 1) * 512 * 1024; // write: h1(s)

    // L0: z = h0_prev @ Whh0^T + x @ Wih0^T ; h0 -> H0q and A1p[.,512:]
    layer_phase<512, 32, 544, 512, 512, 1024>(H0p, xp, W0, bs0, c0,
                                              H0q, A1p + 512, m0, row_a, kq);
    gbar(bar, &tgt);
    // L1: z = [h1_prev | h0_new] @ [Whh1 | Wih1]^T ; h1 -> A1q[.,0:512]
    layer_phase<1024, 0, 1024, 1024, 1024, 0>(A1p, nullptr, W1, bs1, c1,
                                              A1q, nullptr, m0, row_a, kq);
    gbar(bar, &tgt);
    if (!enc) {
      fc_phase(A1q, fc1w, fc1b, fc4w, fc4b, out, Xd, s - 96);
      gbar(bar, &tgt);
    }
  }
}

// ---------------- host ----------------
extern "C" void kernel_launch(void* const* d_in, const int* in_sizes, int n_in,
                              void* d_out, int out_size, void* d_ws, size_t ws_size,
                              hipStream_t stream)
{
  // setup_inputs() dict order puts train (size 1) at index 2; tolerate
  // signature order (train last) as a fallback.
  const int base = (in_sizes[2] == 1) ? 3 : 2;
  const float* src   = (const float*)d_in[0];
  const float* eWih0 = (const float*)d_in[base + 0];
  const float* eWhh0 = (const float*)d_in[base + 1];
  const float* ebih0 = (const float*)d_in[base + 2];
  const float* ebhh0 = (const float*)d_in[base + 3];
  const float* eWih1 = (const float*)d_in[base + 4];
  const float* eWhh1 = (const float*)d_in[base + 5];
  const float* ebih1 = (const float*)d_in[base + 6];
  const float* ebhh1 = (const float*)d_in[base + 7];
  const float* dWih0 = (const float*)d_in[base + 8];
  const float* dWhh0 = (const float*)d_in[base + 9];
  const float* dbih0 = (const float*)d_in[base + 10];
  const float* dbhh0 = (const float*)d_in[base + 11];
  const float* dWih1 = (const float*)d_in[base + 12];
  const float* dWhh1 = (const float*)d_in[base + 13];
  const float* dbih1 = (const float*)d_in[base + 14];
  const float* dbhh1 = (const float*)d_in[base + 15];
  const float* fc1w  = (const float*)d_in[base + 16];
  const float* fc1b  = (const float*)d_in[base + 17];
  const float* fc4w  = (const float*)d_in[base + 18];
  const float* fc4b  = (const float*)d_in[base + 19];

  // workspace carve (all chunks 256B-aligned by construction; total ~20.3 MiB)
  char* p = (char*)d_ws;
  _Float16* W0e = (_Float16*)p; p += 2048 * 544 * 2;
  _Float16* W1e = (_Float16*)p; p += 2048 * 1024 * 2;
  _Float16* W0d = (_Float16*)p; p += 2048 * 544 * 2;
  _Float16* W1d = (_Float16*)p; p += 2048 * 1024 * 2;
  float*    bsv = (float*)p;    p += 8192 * 4;
  _Float16* H0  = (_Float16*)p; p += 2 * 512 * 512 * 2;
  _Float16* A1  = (_Float16*)p; p += 2 * 512 * 1024 * 2;
  float*    c0  = (float*)p;    p += 512 * 512 * 4;
  float*    c1  = (float*)p;    p += 512 * 512 * 4;
  _Float16* Xe  = (_Float16*)p; p += 96 * 512 * 32 * 2;
  _Float16* Xd  = (_Float16*)p; p += 512 * 32 * 2;
  unsigned* bar = (unsigned*)p; p += 256;

  hipLaunchKernelGGL(prep_kernel, dim3(1024), dim3(256), 0, stream,
      src, eWih0, eWhh0, ebih0, ebhh0, eWih1, eWhh1, ebih1, ebhh1,
      dWih0, dWhh0, dbih0, dbhh0, dWih1, dWhh1, dbih1, dbhh1,
      W0e, W1e, W0d, W1d, bsv, H0, A1, c0, c1, Xe, Xd, bar);

  float* out = (float*)d_out;
  void* kargs[] = { &W0e, &W1e, &W0d, &W1d, &bsv, &H0, &A1, &c0, &c1,
                    &Xe, &Xd, &fc1w, &fc1b, &fc4w, &fc4b, &out, &bar };
  hipLaunchCooperativeKernel(reinterpret_cast<void*>(lstm_main),
                             dim3(NBLK), dim3(NTHR), kargs, 0, stream);
}

// Round 2
// 4479.650 us; speedup vs baseline: 1.9427x; 1.9427x over previous
//
#include <hip/hip_runtime.h>
#include <hip/hip_bf16.h>

// LSTM Seq2Seq persistent kernel, fp16 MFMA + fp32 cell state. Round 2:
// 1) Barrier fix: RELAXED polls + single acquire fence on exit (the round-1
//    ACQUIRE-per-poll emitted buffer_inv each iteration -> L2 thrash, 33us
//    barriers, 3.3 GB/dispatch refetch).
// 2) Phase merge: encoder computes L0(t) and L1(t-1) in one phase (true
//    pipeline); decoder fuses a redundant per-block FC into the L0 phase.
//    264 -> 144 grid barriers.
// 3) Wave-split (enc): waves 0-1 do L0, waves 2-3 do L1 concurrently.
//    XCD swizzle: colgrp=(blk&7)*4+((blk>>3)&3) so each XCD touches 4/32
//    of the weight columns per phase.

typedef _Float16 half8 __attribute__((ext_vector_type(8)));
typedef float floatx4 __attribute__((ext_vector_type(4)));

#define NBLK 256
#define NTHR 256

__device__ __forceinline__ float sigf(float x) { return 1.f / (1.f + __expf(-x)); }
__device__ __forceinline__ float tanhf_(float x) { return 1.f - 2.f / (__expf(2.f * x) + 1.f); }

// Grid barrier: release-add, relaxed spin, one acquire fence at exit.
__device__ __forceinline__ void gbar(unsigned* bar, unsigned& tgt) {
  __syncthreads();  // drain this block's stores (vmcnt) before release
  if (threadIdx.x == 0) {
    tgt += NBLK;
    __hip_atomic_fetch_add(bar, 1u, __ATOMIC_RELEASE, __HIP_MEMORY_SCOPE_AGENT);
    while (__hip_atomic_load(bar, __ATOMIC_RELAXED, __HIP_MEMORY_SCOPE_AGENT) < tgt)
      __builtin_amdgcn_s_sleep(2);
    __builtin_amdgcn_fence(__ATOMIC_ACQUIRE, "agent");  // one inv, not per-poll
  }
  __syncthreads();
}

// ---------------- prep kernel: fp16 weight repack + transposes + init ----------------
__global__ void prep_kernel(
    const float* __restrict__ src,
    const float* __restrict__ eWih0, const float* __restrict__ eWhh0,
    const float* __restrict__ ebih0, const float* __restrict__ ebhh0,
    const float* __restrict__ eWih1, const float* __restrict__ eWhh1,
    const float* __restrict__ ebih1, const float* __restrict__ ebhh1,
    const float* __restrict__ dWih0, const float* __restrict__ dWhh0,
    const float* __restrict__ dbih0, const float* __restrict__ dbhh0,
    const float* __restrict__ dWih1, const float* __restrict__ dWhh1,
    const float* __restrict__ dbih1, const float* __restrict__ dbhh1,
    const float* __restrict__ fc1w, const float* __restrict__ fc1b,
    const float* __restrict__ fc4w, const float* __restrict__ fc4b,
    _Float16* W0e, _Float16* W1e, _Float16* W0d, _Float16* W1d,
    float* bs, _Float16* A1, float* c0, float* c1,
    _Float16* Xe, _Float16* Xd, _Float16* Wfc, float* bfc, unsigned* bar)
{
  const int T = gridDim.x * blockDim.x;
  const int idx = blockIdx.x * blockDim.x + threadIdx.x;

  // L0 weights: row r = [Whh0[r][0..511] | Wih0[r][0..31]], stride 544
  for (int i = idx; i < 2048 * 544; i += T) {
    int r = i / 544, k = i - r * 544;
    W0e[i] = (_Float16)(k < 512 ? eWhh0[r * 512 + k] : eWih0[r * 32 + k - 512]);
    W0d[i] = (_Float16)(k < 512 ? dWhh0[r * 512 + k] : dWih0[r * 32 + k - 512]);
  }
  // L1 weights: row r = [Whh1[r][0..511] | Wih1[r][0..511]], stride 1024
  for (int i = idx; i < 2048 * 1024; i += T) {
    int r = i >> 10, k = i & 1023;
    W1e[i] = (_Float16)(k < 512 ? eWhh1[r * 512 + k] : eWih1[r * 512 + k - 512]);
    W1d[i] = (_Float16)(k < 512 ? dWhh1[r * 512 + k] : dWih1[r * 512 + k - 512]);
  }
  // combined biases bih+bhh: [b0e | b1e | b0d | b1d]
  for (int i = idx; i < 2048; i += T) {
    bs[i]        = ebih0[i] + ebhh0[i];
    bs[2048 + i] = ebih1[i] + ebhh1[i];
    bs[4096 + i] = dbih0[i] + dbhh0[i];
    bs[6144 + i] = dbih1[i] + dbhh1[i];
  }
  // FC weights: rows 0..31 = fc4w, row 32 = fc1w, rows 33..47 zero (3 n-tiles)
  for (int i = idx; i < 48 * 512; i += T) {
    int r = i >> 9, k = i & 511;
    float v = (r < 32) ? fc4w[r * 512 + k] : (r == 32 ? fc1w[k] : 0.f);
    Wfc[i] = (_Float16)v;
  }
  for (int i = idx; i < 64; i += T)
    bfc[i] = (i < 32) ? fc4b[i] : (i == 32 ? fc1b[0] : 0.f);
  // encoder inputs step-major: Xe[t][b][f] = src[b][t][f]
  for (int i = idx; i < 96 * 512 * 32; i += T) {
    int t = i / (512 * 32); int rem = i - t * 512 * 32; int b = rem >> 5; int f = rem & 31;
    Xe[i] = (_Float16)src[(size_t)b * 96 * 32 + t * 32 + f];
  }
  // decoder x_init = src[:, 95, :]
  for (int i = idx; i < 512 * 32; i += T) {
    int b = i >> 5, f = i & 31;
    Xd[i] = (_Float16)src[(size_t)b * 96 * 32 + 95 * 32 + f];
  }
  // zero states: A1 double buffer rows [h1 | h0], plus cells
  for (int i = idx; i < 2 * 512 * 1024; i += T) A1[i] = (_Float16)0.f;
  for (int i = idx; i < 512 * 512; i += T) { c0[i] = 0.f; c1[i] = 0.f; }
  if (idx == 0) *bar = 0u;
}

// ---------------- fused GEMM + LSTM-gate phase ----------------
// MFMA 16x16x32 f16: A[m=lane&15][k=(lane>>4)*8+j], B[n=lane&15][k=...],
// D: col=lane&15, row=(lane>>4)*4+reg.  A/dst row stride 1024, X stride 32.
template <int WS, int KH, bool XP, int T>
__device__ __forceinline__ void layer_phase(
    const _Float16* __restrict__ A, const _Float16* __restrict__ X,
    const _Float16* __restrict__ W, const float* __restrict__ bsum,
    float* __restrict__ c, _Float16* __restrict__ dst,
    int m0, int row_a, int kq, int n)
{
  floatx4 acc[T][4];
#pragma unroll
  for (int t = 0; t < T; ++t)
#pragma unroll
    for (int g = 0; g < 4; ++g) {
      float b = bsum[g * 512 + n];
      acc[t][g] = (floatx4){b, b, b, b};
    }
  const _Float16* ar[T];
#pragma unroll
  for (int t = 0; t < T; ++t) ar[t] = A + (size_t)(m0 + t * 16 + row_a) * 1024 + kq * 8;
  const _Float16* wr[4];
#pragma unroll
  for (int g = 0; g < 4; ++g) wr[g] = W + (size_t)(g * 512 + n) * WS + kq * 8;

#pragma unroll 8
  for (int k0 = 0; k0 < KH; k0 += 32) {
    half8 b0 = *(const half8*)(wr[0] + k0);
    half8 b1 = *(const half8*)(wr[1] + k0);
    half8 b2 = *(const half8*)(wr[2] + k0);
    half8 b3 = *(const half8*)(wr[3] + k0);
#pragma unroll
    for (int t = 0; t < T; ++t) {
      half8 af = *(const half8*)(ar[t] + k0);
      acc[t][0] = __builtin_amdgcn_mfma_f32_16x16x32_f16(af, b0, acc[t][0], 0, 0, 0);
      acc[t][1] = __builtin_amdgcn_mfma_f32_16x16x32_f16(af, b1, acc[t][1], 0, 0, 0);
      acc[t][2] = __builtin_amdgcn_mfma_f32_16x16x32_f16(af, b2, acc[t][2], 0, 0, 0);
      acc[t][3] = __builtin_amdgcn_mfma_f32_16x16x32_f16(af, b3, acc[t][3], 0, 0, 0);
    }
  }
  if constexpr (XP) {  // x-part: one K=32 chunk, weights at row offset KH
    half8 b0 = *(const half8*)(wr[0] + KH);
    half8 b1 = *(const half8*)(wr[1] + KH);
    half8 b2 = *(const half8*)(wr[2] + KH);
    half8 b3 = *(const half8*)(wr[3] + KH);
#pragma unroll
    for (int t = 0; t < T; ++t) {
      half8 af = *(const half8*)(X + (size_t)(m0 + t * 16 + row_a) * 32 + kq * 8);
      acc[t][0] = __builtin_amdgcn_mfma_f32_16x16x32_f16(af, b0, acc[t][0], 0, 0, 0);
      acc[t][1] = __builtin_amdgcn_mfma_f32_16x16x32_f16(af, b1, acc[t][1], 0, 0, 0);
      acc[t][2] = __builtin_amdgcn_mfma_f32_16x16x32_f16(af, b2, acc[t][2], 0, 0, 0);
      acc[t][3] = __builtin_amdgcn_mfma_f32_16x16x32_f16(af, b3, acc[t][3], 0, 0, 0);
    }
  }
  // fused LSTM gate epilogue (i,f,g,o)
#pragma unroll
  for (int t = 0; t < T; ++t)
#pragma unroll
    for (int j = 0; j < 4; ++j) {
      int br = m0 + t * 16 + kq * 4 + j;
      float iv = acc[t][0][j], fv = acc[t][1][j], gv = acc[t][2][j], ov = acc[t][3][j];
      float* cp = c + (size_t)br * 512 + n;
      float cn = sigf(fv) * (*cp) + sigf(iv) * tanhf_(gv);
      float hn = sigf(ov) * tanhf_(cn);
      *cp = cn;
      dst[(size_t)br * 1024 + n] = (_Float16)hn;
    }
}

// ---------------- decoder FC heads via MFMA (redundant per block) ----------------
// Computes x(d+1)=fc4(h1) into Xd (own 16 rows per wave) and out1=fc1(h1).
__device__ __forceinline__ void fc_phase(
    const _Float16* __restrict__ h1, const _Float16* __restrict__ Wfc,
    const float* __restrict__ bfc, float* __restrict__ out,
    _Float16* __restrict__ Xd, int m0, int row_a, int kq, bool wr_out, int d)
{
  floatx4 acc[3];
#pragma unroll
  for (int nt = 0; nt < 3; ++nt) {
    float b = bfc[nt * 16 + row_a];
    acc[nt] = (floatx4){b, b, b, b};
  }
  const _Float16* arow = h1 + (size_t)(m0 + row_a) * 1024 + kq * 8;
  const _Float16* wrow[3];
#pragma unroll
  for (int nt = 0; nt < 3; ++nt) wrow[nt] = Wfc + (size_t)(nt * 16 + row_a) * 512 + kq * 8;
#pragma unroll 8
  for (int k0 = 0; k0 < 512; k0 += 32) {
    half8 af = *(const half8*)(arow + k0);
    half8 b0 = *(const half8*)(wrow[0] + k0);
    half8 b1 = *(const half8*)(wrow[1] + k0);
    half8 b2 = *(const half8*)(wrow[2] + k0);
    acc[0] = __builtin_amdgcn_mfma_f32_16x16x32_f16(af, b0, acc[0], 0, 0, 0);
    acc[1] = __builtin_amdgcn_mfma_f32_16x16x32_f16(af, b1, acc[1], 0, 0, 0);
    acc[2] = __builtin_amdgcn_mfma_f32_16x16x32_f16(af, b2, acc[2], 0, 0, 0);
  }
#pragma unroll
  for (int nt = 0; nt < 3; ++nt) {
    int col = nt * 16 + row_a;
#pragma unroll
    for (int j = 0; j < 4; ++j) {
      int row = m0 + kq * 4 + j;
      if (col < 32) Xd[row * 32 + col] = (_Float16)acc[nt][j];
      else if (col == 32 && wr_out) out[row * 24 + d] = acc[nt][j];
    }
  }
}

// ---------------- persistent recurrence kernel ----------------
__global__ void __launch_bounds__(NTHR, 1) lstm_main(
    const _Float16* __restrict__ W0e, const _Float16* __restrict__ W1e,
    const _Float16* __restrict__ W0d, const _Float16* __restrict__ W1d,
    const float* __restrict__ bs, _Float16* A1, float* c0, float* c1,
    const _Float16* __restrict__ Xe, _Float16* Xd,
    const _Float16* __restrict__ Wfc, const float* __restrict__ bfc,
    float* out, unsigned* bar)
{
  const int tid = threadIdx.x;
  const int lane = tid & 63, wv = tid >> 6;
  const int blk = (int)blockIdx.x;
  const int rowg = blk >> 5;                       // 0..7 batch group
  const int colg = (blk & 7) * 4 + ((blk >> 3) & 3);  // 0..31, XCD-local cols
  const int mbase = rowg * 64;
  const int row_a = lane & 15, kq = lane >> 4;
  const int n = colg * 16 + row_a;
  unsigned tgt = 0;

  _Float16* bufR = A1;
  _Float16* bufW = A1 + (size_t)512 * 1024;

  // ---- encoder pipeline: phase t computes L0(t) [t<=96] and L1(t-1) [t>=1].
  // t==96's "L0" is the first decoder L0 (x = x_init), L1 is enc L1(95).
  for (int t = 0; t < 97; ++t) {
    const bool dec0 = (t == 96);
    if (wv < 2) {
      layer_phase<544, 512, true, 2>(
          bufR + 512, dec0 ? Xd : Xe + (size_t)t * 512 * 32,
          dec0 ? W0d : W0e, bs + (dec0 ? 4096 : 0), c0,
          bufW + 512, mbase + wv * 32, row_a, kq, n);
    } else if (t >= 1) {
      layer_phase<1024, 1024, false, 2>(
          bufR, nullptr, W1e, bs + 2048, c1,
          bufW, mbase + (wv - 2) * 32, row_a, kq, n);
    }
    gbar(bar, tgt);
    _Float16* tmp = bufR; bufR = bufW; bufW = tmp;
  }

  // ---- decoder: 2 phases per step.
  for (int d = 0; d < 24; ++d) {
    // Phase A: h1(d) = L1d(h1(d-1), h0(d));  bufR = [h1(d-1) | h0(d)]
    layer_phase<1024, 1024, false, 1>(
        bufR, nullptr, W1d, bs + 6144, c1,
        bufW, mbase + wv * 16, row_a, kq, n);
    gbar(bar, tgt);
    // Phase B: FC heads on h1(d) (redundant per block), then L0d(d+1)
    fc_phase(bufW, Wfc, bfc, out, Xd, mbase + wv * 16, row_a, kq, colg == 0, d);
    __syncthreads();  // own-block Xd writes -> visible to own L0 loads
    if (d < 23) {
      layer_phase<544, 512, true, 1>(
          bufR + 512, Xd, W0d, bs + 4096, c0,
          bufW + 512, mbase + wv * 16, row_a, kq, n);
      gbar(bar, tgt);
    }
    _Float16* tmp = bufR; bufR = bufW; bufW = tmp;
  }
}

// ---------------- host ----------------
extern "C" void kernel_launch(void* const* d_in, const int* in_sizes, int n_in,
                              void* d_out, int out_size, void* d_ws, size_t ws_size,
                              hipStream_t stream)
{
  const int base = (in_sizes[2] == 1) ? 3 : 2;
  const float* src   = (const float*)d_in[0];
  const float* eWih0 = (const float*)d_in[base + 0];
  const float* eWhh0 = (const float*)d_in[base + 1];
  const float* ebih0 = (const float*)d_in[base + 2];
  const float* ebhh0 = (const float*)d_in[base + 3];
  const float* eWih1 = (const float*)d_in[base + 4];
  const float* eWhh1 = (const float*)d_in[base + 5];
  const float* ebih1 = (const float*)d_in[base + 6];
  const float* ebhh1 = (const float*)d_in[base + 7];
  const float* dWih0 = (const float*)d_in[base + 8];
  const float* dWhh0 = (const float*)d_in[base + 9];
  const float* dbih0 = (const float*)d_in[base + 10];
  const float* dbhh0 = (const float*)d_in[base + 11];
  const float* dWih1 = (const float*)d_in[base + 12];
  const float* dWhh1 = (const float*)d_in[base + 13];
  const float* dbih1 = (const float*)d_in[base + 14];
  const float* dbhh1 = (const float*)d_in[base + 15];
  const float* fc1w  = (const float*)d_in[base + 16];
  const float* fc1b  = (const float*)d_in[base + 17];
  const float* fc4w  = (const float*)d_in[base + 18];
  const float* fc4b  = (const float*)d_in[base + 19];

  char* p = (char*)d_ws;
  _Float16* W0e = (_Float16*)p; p += 2048 * 544 * 2;
  _Float16* W1e = (_Float16*)p; p += 2048 * 1024 * 2;
  _Float16* W0d = (_Float16*)p; p += 2048 * 544 * 2;
  _Float16* W1d = (_Float16*)p; p += 2048 * 1024 * 2;
  float*    bsv = (float*)p;    p += 8192 * 4;
  _Float16* A1  = (_Float16*)p; p += 2 * 512 * 1024 * 2;
  float*    c0  = (float*)p;    p += 512 * 512 * 4;
  float*    c1  = (float*)p;    p += 512 * 512 * 4;
  _Float16* Xe  = (_Float16*)p; p += 96 * 512 * 32 * 2;
  _Float16* Xd  = (_Float16*)p; p += 512 * 32 * 2;
  _Float16* Wfc = (_Float16*)p; p += 48 * 512 * 2;
  float*    bfc = (float*)p;    p += 64 * 4;
  unsigned* bar = (unsigned*)p; p += 256;

  hipLaunchKernelGGL(prep_kernel, dim3(1024), dim3(256), 0, stream,
      src, eWih0, eWhh0, ebih0, ebhh0, eWih1, eWhh1, ebih1, ebhh1,
      dWih0, dWhh0, dbih0, dbhh0, dWih1, dWhh1, dbih1, dbhh1,
      fc1w, fc1b, fc4w, fc4b,
      W0e, W1e, W0d, W1d, bsv, A1, c0, c1, Xe, Xd, Wfc, bfc, bar);

  float* out = (float*)d_out;
  void* kargs[] = { &W0e, &W1e, &W0d, &W1d, &bsv, &A1, &c0, &c1,
                    &Xe, &Xd, &Wfc, &bfc, &out, &bar };
  hipLaunchCooperativeKernel(reinterpret_cast<void*>(lstm_main),
                             dim3(NBLK), dim3(NTHR), kargs, 0, stream);
}